// Round 2
// baseline (4045.185 us; speedup 1.0000x reference)
//
#include <hip/hip_runtime.h>
#include <cstring>

#define NQ 16
#define NLAYERS 8
#define BATCHN 512
#define LB 13
#define NLOC (1<<LB)
#define NCHUNK (1<<(NQ-LB))
#define NTHREADS 256

typedef unsigned u32;

// Fused-pass descriptor. Pass p: [prev-layer deferred Rots] -> [tau = deferred CNOTs,
// folded into gather addresses] -> [current-layer local Rots] -> [applied-CNOT fold on write].
struct PD {
  int layerA, layerB, mode, contig;   // mode: 0 mid, 1 init(embed), 2 fin(readout)
  int qop[13];      // qubit at local position
  int glb[3];       // global (chunk) qubits, ascending
  int r1d[3];       // R1 tile dir positions (prev-gate positions), ascending
  int r1q[3];       // prev qubits matching r1d
  int r1f[8];       // R1 free positions (tid bits -> these positions)
  u32 tinv[13];     // tau^{-1} local masks per position basis (R2/R2b gather)
  u32 cinv[13];     // mid: (tau^{-1} o A^{-1}) local masks (R3); fin: full fwd masks (readout)
};

__device__ __forceinline__ u32 swz(u32 q){ return q ^ ((q >> 3) & 7u); }

template<int J>
__device__ __forceinline__ void apply_gate(float2 (&a)[32],
  float M0r,float M0i,float M1r,float M1i,float M2r,float M2i,float M3r,float M3i){
  #pragma unroll
  for (int bb=0;bb<32;bb++){
    if ((bb>>J)&1) continue;
    const int i0=bb, i1=bb|(1<<J);
    float ar=a[i0].x, ai=a[i0].y, br=a[i1].x, bi=a[i1].y;
    a[i0].x = M0r*ar - M0i*ai + M1r*br - M1i*bi;
    a[i0].y = M0r*ai + M0i*ar + M1r*bi + M1i*br;
    a[i1].x = M2r*ar - M2i*ai + M3r*br - M3i*bi;
    a[i1].y = M2r*ai + M2i*ar + M3r*bi + M3i*br;
  }
}

// fetch 2x2 complex matrix from lane SRC and apply on tile bit J
#define APPLY(J, SRC) { \
  int _s = (SRC); \
  float r0=__shfl(mm0,_s), i0=__shfl(mm1,_s), r1=__shfl(mm2,_s), i1=__shfl(mm3,_s); \
  float r2=__shfl(mm4,_s), i2=__shfl(mm5,_s), r3=__shfl(mm6,_s), i3=__shfl(mm7,_s); \
  apply_gate<J>(a, r0,i0,r1,i1,r2,i2,r3,i3); }

__global__ __launch_bounds__(NTHREADS)
void qpass(const float* __restrict__ x, const float* __restrict__ w,
           float2* __restrict__ state, float* __restrict__ out, PD pd)
{
  __shared__ __align__(16) float2 st[NLOC];   // 64 KB
  const int tid = threadIdx.x;
  const u32 chunk = blockIdx.x;
  const int b = blockIdx.y;
  float2* __restrict__ gst = state + ((size_t)b << NQ);

  // per-lane Rot matrices: lanes 0-15 = layerA (prev), 16-31 = layerB (cur)
  float mm0,mm1,mm2,mm3,mm4,mm5,mm6,mm7;
  {
    int lane = tid & 63;
    int q = lane & 15;
    int lay = ((lane>>4)&1) ? pd.layerB : pd.layerA;
    if (lay < 0) lay = 0;
    float phi = w[(lay*NQ+q)*3+0], th = w[(lay*NQ+q)*3+1], om = w[(lay*NQ+q)*3+2];
    float sh, ch; sincosf(0.5f*th, &sh, &ch);
    float spo, cpo; sincosf(-0.5f*(phi+om), &spo, &cpo);
    float smo, cmo; sincosf(-0.5f*(phi-om), &smo, &cmo);
    mm0 =  cpo*ch; mm1 =  spo*ch;     // m00
    mm2 = -cmo*sh; mm3 =  smo*sh;     // m01
    mm4 =  cmo*sh; mm5 =  smo*sh;     // m10
    mm6 =  cpo*ch; mm7 = -spo*ch;     // m11
  }

  float2 a[32];

  // ================= R1: tiled global read + prev-layer deferred Rots =================
  if (pd.mode != 1){
    u32 ebase = 0, lbase = 0;
    #pragma unroll
    for (int j=0;j<8;j++) if ((tid>>j)&1){ ebase ^= 1u<<pd.qop[pd.r1f[j]]; lbase |= 1u<<pd.r1f[j]; }
    #pragma unroll
    for (int j=0;j<3;j++) if ((chunk>>j)&1) ebase ^= 1u<<pd.glb[j];
    u32 dm0 = 1u<<pd.qop[pd.r1d[0]], dm1 = 1u<<pd.qop[pd.r1d[1]], dm2 = 1u<<pd.qop[pd.r1d[2]];
    #pragma unroll
    for (int g=0; g<8; g++){
      u32 full = ebase ^ ((g&1)?dm0:0u) ^ (((g>>1)&1)?dm1:0u) ^ (((g>>2)&1)?dm2:0u);
      const float4* gp = (const float4*)(gst + full);
      float4 v0 = gp[0], v1 = gp[1];
      a[g*4+0] = make_float2(v0.x,v0.y); a[g*4+1] = make_float2(v0.z,v0.w);
      a[g*4+2] = make_float2(v1.x,v1.y); a[g*4+3] = make_float2(v1.z,v1.w);
    }
    APPLY(2, pd.r1q[0]); APPLY(3, pd.r1q[1]); APPLY(4, pd.r1q[2]);

    if (pd.mode == 2){
      // -------- readout: |amp|^2 with tau-forward index transform --------
      float acc[NQ];
      #pragma unroll
      for (int q=0;q<NQ;q++) acc[q]=0.f;
      u32 nb = 0;
      #pragma unroll
      for (int j=0;j<8;j++) if ((tid>>j)&1) nb ^= pd.cinv[pd.r1f[j]];
      #pragma unroll
      for (int j=0;j<3;j++) if ((chunk>>j)&1) nb ^= 1u<<pd.glb[j];
      u32 cd0 = pd.cinv[pd.r1d[0]], cd1 = pd.cinv[pd.r1d[1]], cd2 = pd.cinv[pd.r1d[2]];
      #pragma unroll
      for (int g=0; g<8; g++){
        u32 n0 = nb ^ ((g&1)?cd0:0u) ^ (((g>>1)&1)?cd1:0u) ^ (((g>>2)&1)?cd2:0u);
        #pragma unroll
        for (int e=0;e<4;e++){
          u32 n = n0 ^ ((e&1)?pd.cinv[0]:0u) ^ (((e>>1)&1)?pd.cinv[1]:0u);
          float2 v = a[g*4+e];
          float p = v.x*v.x + v.y*v.y;
          #pragma unroll
          for (int q=0;q<NQ;q++) acc[q] += ((n>>q)&1u) ? -p : p;
        }
      }
      #pragma unroll
      for (int q=0;q<NQ;q++){
        float v = acc[q];
        #pragma unroll
        for (int off=32; off; off>>=1) v += __shfl_xor(v, off);
        if ((tid & 63) == 0) atomicAdd(&out[b*NQ+q], v);
      }
      return;
    }
    // write tile to LDS (logical, pre-tau layout)
    u32 ld0 = 1u<<pd.r1d[0], ld1 = 1u<<pd.r1d[1], ld2 = 1u<<pd.r1d[2];
    #pragma unroll
    for (int g=0; g<8; g++){
      u32 m = lbase | ((g&1)?ld0:0u) | (((g>>1)&1)?ld1:0u) | (((g>>2)&1)?ld2:0u);
      u32 p2 = swz(m>>2)*2u;
      ((float4*)st)[p2  ] = make_float4(a[g*4+0].x,a[g*4+0].y,a[g*4+1].x,a[g*4+1].y);
      ((float4*)st)[p2+1] = make_float4(a[g*4+2].x,a[g*4+2].y,a[g*4+3].x,a[g*4+3].y);
    }
    __syncthreads();
  }

  // ================= R2: 11 current-layer gates (5 tile + 6 lane) =================
  u32 sb = 0;
  #pragma unroll
  for (int j=0;j<8;j++) if ((tid>>j)&1) sb ^= pd.tinv[2+j];
  u32 td0 = pd.tinv[10], td1 = pd.tinv[11], td2 = pd.tinv[12];

  if (pd.mode == 1){
    // embed: generate product state directly into the R2 tile
    float ca[NQ], sa[NQ];
    #pragma unroll
    for (int q=0;q<NQ;q++){
      float aa = 1.57079632679489662f * x[b*NQ+q];
      sincosf(aa, &sa[q], &ca[q]);
    }
    float vt = 1.f;
    #pragma unroll
    for (int j=0;j<8;j++){ int q = pd.qop[2+j]; vt *= ((tid>>j)&1)? sa[q] : ca[q]; }
    #pragma unroll
    for (int j=0;j<3;j++){ int q = pd.glb[j]; vt *= ((chunk>>j)&1)? sa[q] : ca[q]; }
    float c0 = ca[pd.qop[0]], s0 = sa[pd.qop[0]], c1 = ca[pd.qop[1]], s1 = sa[pd.qop[1]];
    float fc10 = ca[pd.qop[10]], fs10 = sa[pd.qop[10]];
    float fc11 = ca[pd.qop[11]], fs11 = sa[pd.qop[11]];
    float fc12 = ca[pd.qop[12]], fs12 = sa[pd.qop[12]];
    #pragma unroll
    for (int g=0; g<8; g++){
      float vg = vt * ((g&1)? fs10 : fc10) * (((g>>1)&1)? fs11 : fc11) * (((g>>2)&1)? fs12 : fc12);
      a[g*4+0] = make_float2(vg*c0*c1, 0.f);
      a[g*4+1] = make_float2(vg*s0*c1, 0.f);
      a[g*4+2] = make_float2(vg*c0*s1, 0.f);
      a[g*4+3] = make_float2(vg*s0*s1, 0.f);
    }
  } else {
    #pragma unroll
    for (int g=0; g<8; g++){
      u32 s = sb ^ ((g&1)?td0:0u) ^ (((g>>1)&1)?td1:0u) ^ (((g>>2)&1)?td2:0u);
      if (pd.contig){
        u32 p2 = swz(s>>2)*2u;
        float4 v0 = ((float4*)st)[p2], v1 = ((float4*)st)[p2+1];
        float2 w0=make_float2(v0.x,v0.y), w1=make_float2(v0.z,v0.w);
        float2 w2=make_float2(v1.x,v1.y), w3=make_float2(v1.z,v1.w);
        u32 sl = s & 3u;
        if (sl & 1){ float2 t=w0; w0=w1; w1=t; t=w2; w2=w3; w3=t; }
        if (sl & 2){ float2 t=w0; w0=w2; w2=t; t=w1; w1=w3; w3=t; }
        a[g*4+0]=w0; a[g*4+1]=w1; a[g*4+2]=w2; a[g*4+3]=w3;
      } else {
        #pragma unroll
        for (int e=0;e<4;e++){
          u32 se = s ^ ((e&1)?pd.tinv[0]:0u) ^ (((e>>1)&1)?pd.tinv[1]:0u);
          a[g*4+e] = st[swz(se>>2)*4u + (se&3u)];
        }
      }
    }
  }

  // tile gates: positions 0,1,10,11,12 (cur layer)
  APPLY(0, 16+pd.qop[0]);  APPLY(1, 16+pd.qop[1]);
  APPLY(2, 16+pd.qop[10]); APPLY(3, 16+pd.qop[11]); APPLY(4, 16+pd.qop[12]);
  // lane gates: positions 2..7 via shfl_xor
  #pragma unroll
  for (int j=0;j<6;j++){
    int q = 16 + pd.qop[2+j];
    float r0=__shfl(mm0,q), i0=__shfl(mm1,q), r1=__shfl(mm2,q), i1=__shfl(mm3,q);
    float r2=__shfl(mm4,q), i2=__shfl(mm5,q), r3=__shfl(mm6,q), i3=__shfl(mm7,q);
    int bit = (tid >> j) & 1;
    float cAr = bit? r3 : r0, cAi = bit? i3 : i0;
    float cBr = bit? r2 : r1, cBi = bit? i2 : i1;
    #pragma unroll
    for (int i=0;i<32;i++){
      float tx = __shfl_xor(a[i].x, 1<<j);
      float ty = __shfl_xor(a[i].y, 1<<j);
      float ax = a[i].x, ay = a[i].y;
      a[i].x = cAr*ax - cAi*ay + cBr*tx - cBi*ty;
      a[i].y = cAr*ay + cAi*ax + cBr*ty + cBi*tx;
    }
  }

  // write back (same addresses)
  #pragma unroll
  for (int g=0; g<8; g++){
    u32 s = sb ^ ((g&1)?td0:0u) ^ (((g>>1)&1)?td1:0u) ^ (((g>>2)&1)?td2:0u);
    if (pd.contig){
      float2 w0=a[g*4+0], w1=a[g*4+1], w2=a[g*4+2], w3=a[g*4+3];
      u32 sl = s & 3u;
      if (sl & 1){ float2 t=w0; w0=w1; w1=t; t=w2; w2=w3; w3=t; }
      if (sl & 2){ float2 t=w0; w0=w2; w2=t; t=w1; w1=w3; w3=t; }
      u32 p2 = swz(s>>2)*2u;
      ((float4*)st)[p2  ] = make_float4(w0.x,w0.y,w1.x,w1.y);
      ((float4*)st)[p2+1] = make_float4(w2.x,w2.y,w3.x,w3.y);
    } else {
      #pragma unroll
      for (int e=0;e<4;e++){
        u32 se = s ^ ((e&1)?pd.tinv[0]:0u) ^ (((e>>1)&1)?pd.tinv[1]:0u);
        st[swz(se>>2)*4u + (se&3u)] = a[g*4+e];
      }
    }
  }
  __syncthreads();

  // ================= R2b: 2 remaining gates (positions 8,9) =================
  {
    u32 sb2 = 0;
    #pragma unroll
    for (int j=0;j<6;j++) if ((tid>>j)&1) sb2 ^= pd.tinv[2+j];
    if ((tid>>6)&1) sb2 ^= pd.tinv[11];
    if ((tid>>7)&1) sb2 ^= pd.tinv[12];
    u32 e0 = pd.tinv[8], e1 = pd.tinv[9], e2 = pd.tinv[10];
    #pragma unroll
    for (int g=0; g<8; g++){
      u32 s = sb2 ^ ((g&1)?e0:0u) ^ (((g>>1)&1)?e1:0u) ^ (((g>>2)&1)?e2:0u);
      if (pd.contig){
        u32 p2 = swz(s>>2)*2u;
        float4 v0 = ((float4*)st)[p2], v1 = ((float4*)st)[p2+1];
        float2 w0=make_float2(v0.x,v0.y), w1=make_float2(v0.z,v0.w);
        float2 w2=make_float2(v1.x,v1.y), w3=make_float2(v1.z,v1.w);
        u32 sl = s & 3u;
        if (sl & 1){ float2 t=w0; w0=w1; w1=t; t=w2; w2=w3; w3=t; }
        if (sl & 2){ float2 t=w0; w0=w2; w2=t; t=w1; w1=w3; w3=t; }
        a[g*4+0]=w0; a[g*4+1]=w1; a[g*4+2]=w2; a[g*4+3]=w3;
      } else {
        #pragma unroll
        for (int e=0;e<4;e++){
          u32 se = s ^ ((e&1)?pd.tinv[0]:0u) ^ (((e>>1)&1)?pd.tinv[1]:0u);
          a[g*4+e] = st[swz(se>>2)*4u + (se&3u)];
        }
      }
    }
    APPLY(2, 16+pd.qop[8]); APPLY(3, 16+pd.qop[9]);
    #pragma unroll
    for (int g=0; g<8; g++){
      u32 s = sb2 ^ ((g&1)?e0:0u) ^ (((g>>1)&1)?e1:0u) ^ (((g>>2)&1)?e2:0u);
      if (pd.contig){
        float2 w0=a[g*4+0], w1=a[g*4+1], w2=a[g*4+2], w3=a[g*4+3];
        u32 sl = s & 3u;
        if (sl & 1){ float2 t=w0; w0=w1; w1=t; t=w2; w2=w3; w3=t; }
        if (sl & 2){ float2 t=w0; w0=w2; w2=t; t=w1; w1=w3; w3=t; }
        u32 p2 = swz(s>>2)*2u;
        ((float4*)st)[p2  ] = make_float4(w0.x,w0.y,w1.x,w1.y);
        ((float4*)st)[p2+1] = make_float4(w2.x,w2.y,w3.x,w3.y);
      } else {
        #pragma unroll
        for (int e=0;e<4;e++){
          u32 se = s ^ ((e&1)?pd.tinv[0]:0u) ^ (((e>>1)&1)?pd.tinv[1]:0u);
          st[swz(se>>2)*4u + (se&3u)] = a[g*4+e];
        }
      }
    }
    __syncthreads();
  }

  // ================= R3: stage-out, applied-CNOT + tau fold on read =================
  {
    u32 ctid = 0, etid = 0;
    #pragma unroll
    for (int j=0;j<8;j++) if ((tid>>j)&1){ ctid ^= pd.cinv[2+j]; etid ^= 1u<<pd.qop[2+j]; }
    #pragma unroll
    for (int j=0;j<3;j++) if ((chunk>>j)&1) etid ^= 1u<<pd.glb[j];
    u32 c10 = pd.cinv[10], c11 = pd.cinv[11], c12 = pd.cinv[12];
    u32 q10 = 1u<<pd.qop[10], q11 = 1u<<pd.qop[11], q12 = 1u<<pd.qop[12];
    #pragma unroll
    for (int j=0;j<8;j++){
      u32 src   = ctid ^ ((j&1)?c10:0u) ^ (((j>>1)&1)?c11:0u) ^ (((j>>2)&1)?c12:0u);
      u32 ofull = etid ^ ((j&1)?q10:0u) ^ (((j>>1)&1)?q11:0u) ^ (((j>>2)&1)?q12:0u);
      float2 vv0, vv1, vv2, vv3;
      {
        u32 s0_ = src;
        u32 s1_ = src ^ pd.cinv[0];
        u32 s2_ = src ^ pd.cinv[1];
        u32 s3_ = src ^ pd.cinv[0] ^ pd.cinv[1];
        vv0 = st[swz(s0_>>2)*4u + (s0_&3u)];
        vv1 = st[swz(s1_>>2)*4u + (s1_&3u)];
        vv2 = st[swz(s2_>>2)*4u + (s2_&3u)];
        vv3 = st[swz(s3_>>2)*4u + (s3_&3u)];
      }
      float4* gp = (float4*)(gst + ofull);
      gp[0] = make_float4(vv0.x,vv0.y,vv1.x,vv1.y);
      gp[1] = make_float4(vv2.x,vv2.y,vv3.x,vv3.y);
    }
  }
}

// ======================= host side =======================

// Fused 9-pass schedule (hand-verified against CNOT ordering constraints):
// G[p] = global qubits of pass p; D[l] = deferred CNOT gate indices of layer l
// (gate i = CNOT(i, (i+r)%16), r = l+1), closure: i in D => i+r in D (if <=15),
// and i+16-r in D (if i < r). A[l] = complement, applied in pass l's write fold.
static const int Gs[9][3] = {
  {13,14,15},{9,10,11},{2,5,6},{4,7,13},{2,10,14},{6,8,11},{3,9,13},{5,7,14},{10,11,12}
};
static const int Dlen[8] = {4,9,10,10,9,10,9,6};
static const int Dl[8][10] = {
  {12,13,14,15,0,0,0,0,0,0},
  {7,8,9,10,11,12,13,14,15,0},
  {2,3,5,6,8,9,11,12,14,15},
  {0,3,4,7,8,9,11,12,13,15},
  {2,5,7,9,10,12,13,14,15,0},
  {0,2,5,6,8,10,11,12,14,15},
  {2,3,6,9,10,11,12,13,15,0},
  {5,6,7,13,14,15,0,0,0,0},
};

static inline u32 apply_cnot_idx(u32 v, int c, int t){ return v ^ (((v>>c)&1u)<<t); }

extern "C" void kernel_launch(void* const* d_in, const int* in_sizes, int n_in,
                              void* d_out, int out_size, void* d_ws, size_t ws_size,
                              hipStream_t stream)
{
  (void)in_sizes; (void)n_in; (void)ws_size;
  const float* x = (const float*)d_in[0];
  const float* w = (const float*)d_in[1];
  float* out = (float*)d_out;
  float2* state = (float2*)d_ws;   // 512 * 65536 * 8B = 256 MiB

  hipMemsetAsync(d_out, 0, (size_t)out_size*sizeof(float), stream);

  for (int p=0; p<9; p++){
    PD pd; memset(&pd, 0, sizeof(pd));
    pd.layerA = p-1;
    pd.layerB = (p<=7)? p : -1;
    pd.mode = (p==0)? 1 : ((p==8)? 2 : 0);

    u32 gm = 0;
    for (int i=0;i<3;i++){ pd.glb[i] = Gs[p][i]; gm |= 1u<<Gs[p][i]; }
    int np=0;
    for (int q=0;q<16;q++) if (!((gm>>q)&1u)) pd.qop[np++] = q;

    // R1 geometry (prev-layer gates)
    if (p >= 1){
      int pos[3], qq[3];
      for (int i=0;i<3;i++){
        int q = Gs[p-1][i]; qq[i] = q;
        int c=0; for (int k=0;k<q;k++) if ((gm>>k)&1u) c++;
        pos[i] = q - c;
      }
      for (int i=0;i<3;i++) for (int k=i+1;k<3;k++)
        if (pos[k] < pos[i]){ int t=pos[i];pos[i]=pos[k];pos[k]=t; t=qq[i];qq[i]=qq[k];qq[k]=t; }
      for (int i=0;i<3;i++){ pd.r1d[i]=pos[i]; pd.r1q[i]=qq[i]; }
      int nf=0;
      for (int pp=2;pp<13;pp++)
        if (pp!=pos[0] && pp!=pos[1] && pp!=pos[2]) pd.r1f[nf++]=pp;
    } else {
      pd.r1d[0]=10; pd.r1d[1]=11; pd.r1d[2]=12;
      for (int j=0;j<8;j++) pd.r1f[j]=2+j;
    }

    // tinv: tau^{-1} (deferred CNOTs of layer p-1, reverse order), compressed to local13
    if (p == 0){
      for (int bp=0;bp<13;bp++) pd.tinv[bp] = 1u<<bp;
    } else {
      int r = p;  // layer (p-1) has r = p
      for (int bp=0;bp<13;bp++){
        u32 v = 1u<<pd.qop[bp];
        for (int i=Dlen[p-1]-1;i>=0;i--){ int c=Dl[p-1][i]; v = apply_cnot_idx(v, c, (c+r)&15); }
        u32 lv=0; for (int rr=0;rr<13;rr++) lv |= ((v>>pd.qop[rr])&1u)<<rr;
        pd.tinv[bp] = lv;
      }
    }
    pd.contig = (pd.tinv[0]==1u && pd.tinv[1]==2u) ? 1 : 0;

    // cinv
    if (p <= 7){
      // R3 chain: first A_p^{-1} (applied CNOTs, reverse order), then tau^{-1}
      int r = p+1;
      bool inD[16]; for (int i=0;i<16;i++) inD[i]=false;
      for (int i=0;i<Dlen[p];i++) inD[Dl[p][i]] = true;
      int A[16], na=0;
      for (int i=0;i<16;i++) if (!inD[i]) A[na++]=i;
      for (int bp=0;bp<13;bp++){
        u32 v = 1u<<pd.qop[bp];
        for (int i=na-1;i>=0;i--){ int c=A[i]; v = apply_cnot_idx(v, c, (c+r)&15); }
        if (p >= 1){
          int rp = p;
          for (int i=Dlen[p-1]-1;i>=0;i--){ int c=Dl[p-1][i]; v = apply_cnot_idx(v, c, (c+rp)&15); }
        }
        u32 lv=0; for (int rr=0;rr<13;rr++) lv |= ((v>>pd.qop[rr])&1u)<<rr;
        pd.cinv[bp] = lv;
      }
    } else {
      // pass 8 readout: full forward tau (D_7 ascending, r=8), uncompressed
      for (int bp=0;bp<13;bp++){
        u32 v = 1u<<pd.qop[bp];
        for (int i=0;i<Dlen[7];i++){ int c=Dl[7][i]; v = apply_cnot_idx(v, c, (c+8)&15); }
        pd.cinv[bp] = v;
      }
    }

    hipLaunchKernelGGL(qpass, dim3(NCHUNK, BATCHN), dim3(NTHREADS), 0, stream,
                       x, w, state, out, pd);
  }
}

// Round 3
// 3269.820 us; speedup vs baseline: 1.2371x; 1.2371x over previous
//
#include <hip/hip_runtime.h>
#include <cstring>

#define NQ 16
#define NLAYERS 8
#define BATCHN 512
#define GROUPB 128                 // batches per L3-resident group (64 MiB slice)
#define NGROUP (BATCHN/GROUPB)
#define LB 13
#define NLOC (1<<LB)
#define NCHUNK (1<<(NQ-LB))
#define NTHREADS 512

typedef unsigned u32;

// Pass p: [prev-layer 3 deferred Rots] -> [tau = deferred CNOTs folded into LDS gather]
// -> [13 local Rots] -> [applied-CNOT fold on write]. Same schedule as round 2,
// re-tiled for 512 threads / 16-amp tiles.
struct PD {
  int layerA, layerB, mode, contig, b0;  // mode: 0 mid, 1 init, 2 fin
  int qop[13];        // qubit at local position
  int glb[3];         // global (chunk) qubits, ascending
  int r1dPos[2];      // R1 tile-dir positions (2 highest prev-global positions)
  int r1dQ[2];        // their qubits
  int r1lQ;           // R1 lane-gate qubit (lowest-position prev-global)
  int r1f[9];         // R1 thread-bit -> free position (bit0 = pos of r1lQ)
  u32 tinv[13];       // tau^{-1} local masks per position basis
  u32 cinv[13];       // mid: (tau^{-1} o A^{-1}); fin: full fwd masks (readout)
};

__device__ __forceinline__ u32 swz(u32 q){ return q ^ ((q >> 3) & 7u); }

template<int J>
__device__ __forceinline__ void gate16(float2 (&a)[16],
  float M0r,float M0i,float M1r,float M1i,float M2r,float M2i,float M3r,float M3i){
  #pragma unroll
  for (int i=0;i<16;i++){
    if ((i>>J)&1) continue;
    const int i1 = i|(1<<J);
    float ar=a[i].x, ai=a[i].y, br=a[i1].x, bi=a[i1].y;
    a[i].x  = M0r*ar - M0i*ai + M1r*br - M1i*bi;
    a[i].y  = M0r*ai + M0i*ar + M1r*bi + M1i*br;
    a[i1].x = M2r*ar - M2i*ai + M3r*br - M3i*bi;
    a[i1].y = M2r*ai + M2i*ar + M3r*bi + M3i*br;
  }
}

__device__ __forceinline__ void lane_gate16(float2 (&a)[16], int tid, int j,
  float r0,float i0,float r1,float i1,float r2,float i2,float r3,float i3){
  int bit = (tid >> j) & 1;
  float cAr = bit? r3 : r0, cAi = bit? i3 : i0;
  float cBr = bit? r2 : r1, cBi = bit? i2 : i1;
  #pragma unroll
  for (int i=0;i<16;i++){
    float tx = __shfl_xor(a[i].x, 1<<j);
    float ty = __shfl_xor(a[i].y, 1<<j);
    float ax = a[i].x, ay = a[i].y;
    a[i].x = cAr*ax - cAi*ay + cBr*tx - cBi*ty;
    a[i].y = cAr*ay + cAi*ax + cBr*ty + cBi*tx;
  }
}

#define APPLY16(J, SRC) { \
  int _s = (SRC); \
  float r0_=__shfl(mm0,_s), i0_=__shfl(mm1,_s), r1_=__shfl(mm2,_s), i1_=__shfl(mm3,_s); \
  float r2_=__shfl(mm4,_s), i2_=__shfl(mm5,_s), r3_=__shfl(mm6,_s), i3_=__shfl(mm7,_s); \
  gate16<J>(a, r0_,i0_,r1_,i1_,r2_,i2_,r3_,i3_); }

#define LANE16(J, SRC) { \
  int _s = (SRC); \
  float r0_=__shfl(mm0,_s), i0_=__shfl(mm1,_s), r1_=__shfl(mm2,_s), i1_=__shfl(mm3,_s); \
  float r2_=__shfl(mm4,_s), i2_=__shfl(mm5,_s), r3_=__shfl(mm6,_s), i3_=__shfl(mm7,_s); \
  lane_gate16(a, tid, (J), r0_,i0_,r1_,i1_,r2_,i2_,r3_,i3_); }

__global__ __launch_bounds__(NTHREADS, 4)
void qpass(const float* __restrict__ x, const float* __restrict__ w,
           float2* __restrict__ state, float* __restrict__ out, PD pd)
{
  __shared__ __align__(16) float2 st[NLOC];   // 64 KB
  const int tid = threadIdx.x;
  const u32 chunk = blockIdx.x;
  const int b = pd.b0 + blockIdx.y;
  float2* __restrict__ gst = state + ((size_t)b << NQ);

  // per-lane Rot matrices: lanes 0-15 = layerA (prev), 16-31 = layerB (cur)
  float mm0,mm1,mm2,mm3,mm4,mm5,mm6,mm7;
  {
    int lane = tid & 63;
    int q = lane & 15;
    int lay = ((lane>>4)&1) ? pd.layerB : pd.layerA;
    if (lay < 0) lay = 0;
    float phi = w[(lay*NQ+q)*3+0], th = w[(lay*NQ+q)*3+1], om = w[(lay*NQ+q)*3+2];
    float sh, ch; sincosf(0.5f*th, &sh, &ch);
    float spo, cpo; sincosf(-0.5f*(phi+om), &spo, &cpo);
    float smo, cmo; sincosf(-0.5f*(phi-om), &smo, &cmo);
    mm0 =  cpo*ch; mm1 =  spo*ch;
    mm2 = -cmo*sh; mm3 =  smo*sh;
    mm4 =  cmo*sh; mm5 =  smo*sh;
    mm6 =  cpo*ch; mm7 = -spo*ch;
  }

  float2 a[16];

  // ================= R1: global gather + 3 prev-layer deferred Rots =================
  if (pd.mode != 1){
    u32 ebase = 0, lbase = 0;
    #pragma unroll
    for (int j=0;j<9;j++) if ((tid>>j)&1){ ebase ^= 1u<<pd.qop[pd.r1f[j]]; lbase |= 1u<<pd.r1f[j]; }
    #pragma unroll
    for (int j=0;j<3;j++) if ((chunk>>j)&1) ebase ^= 1u<<pd.glb[j];
    u32 dm0 = 1u<<pd.qop[pd.r1dPos[0]], dm1 = 1u<<pd.qop[pd.r1dPos[1]];
    #pragma unroll
    for (int g=0; g<4; g++){
      u32 full = ebase ^ ((g&1)?dm0:0u) ^ (((g>>1)&1)?dm1:0u);
      const float4* gp = (const float4*)(gst + full);
      float4 v0 = gp[0], v1 = gp[1];
      a[g*4+0] = make_float2(v0.x,v0.y); a[g*4+1] = make_float2(v0.z,v0.w);
      a[g*4+2] = make_float2(v1.x,v1.y); a[g*4+3] = make_float2(v1.z,v1.w);
    }
    APPLY16(2, pd.r1dQ[0]);
    APPLY16(3, pd.r1dQ[1]);
    LANE16(0, pd.r1lQ);

    if (pd.mode == 2){
      // -------- readout: |amp|^2, full forward masks in cinv --------
      float acc[NQ];
      #pragma unroll
      for (int q=0;q<NQ;q++) acc[q]=0.f;
      u32 nb = 0;
      #pragma unroll
      for (int j=0;j<9;j++) if ((tid>>j)&1) nb ^= pd.cinv[pd.r1f[j]];
      #pragma unroll
      for (int j=0;j<3;j++) if ((chunk>>j)&1) nb ^= 1u<<pd.glb[j];
      u32 cd0 = pd.cinv[pd.r1dPos[0]], cd1 = pd.cinv[pd.r1dPos[1]];
      #pragma unroll
      for (int g=0; g<4; g++){
        u32 n0 = nb ^ ((g&1)?cd0:0u) ^ (((g>>1)&1)?cd1:0u);
        #pragma unroll
        for (int e=0;e<4;e++){
          u32 n = n0 ^ ((e&1)?pd.cinv[0]:0u) ^ (((e>>1)&1)?pd.cinv[1]:0u);
          float2 v = a[g*4+e];
          float p = v.x*v.x + v.y*v.y;
          #pragma unroll
          for (int q=0;q<NQ;q++) acc[q] += ((n>>q)&1u) ? -p : p;
        }
      }
      #pragma unroll
      for (int q=0;q<NQ;q++){
        float v = acc[q];
        #pragma unroll
        for (int off=32; off; off>>=1) v += __shfl_xor(v, off);
        if ((tid & 63) == 0) atomicAdd(&out[b*NQ+q], v);
      }
      return;
    }

    // write tile to LDS (logical, pre-tau layout)
    u32 ld0 = 1u<<pd.r1dPos[0], ld1 = 1u<<pd.r1dPos[1];
    #pragma unroll
    for (int g=0; g<4; g++){
      u32 m = lbase | ((g&1)?ld0:0u) | (((g>>1)&1)?ld1:0u);
      u32 p2 = swz(m>>2)*2u;
      ((float4*)st)[p2  ] = make_float4(a[g*4+0].x,a[g*4+0].y,a[g*4+1].x,a[g*4+1].y);
      ((float4*)st)[p2+1] = make_float4(a[g*4+2].x,a[g*4+2].y,a[g*4+3].x,a[g*4+3].y);
    }
    __syncthreads();
  }

  // ================= R2: 10 gates (2 e + 2 dir + 6 lane) =================
  // thread bits 0..8 -> positions 2..10; dirs = positions 11,12; e = 0,1
  u32 sb = 0;
  #pragma unroll
  for (int j=0;j<9;j++) if ((tid>>j)&1) sb ^= pd.tinv[2+j];
  u32 tD0 = pd.tinv[11], tD1 = pd.tinv[12];

  if (pd.mode == 1){
    // embed: product state directly in R2 layout
    float ca[NQ], sa[NQ];
    #pragma unroll
    for (int q=0;q<NQ;q++){
      float aa = 1.57079632679489662f * x[b*NQ+q];
      sincosf(aa, &sa[q], &ca[q]);
    }
    float vt = 1.f;
    #pragma unroll
    for (int j=0;j<9;j++){ int q = pd.qop[2+j]; vt *= ((tid>>j)&1)? sa[q] : ca[q]; }
    #pragma unroll
    for (int j=0;j<3;j++){ int q = pd.glb[j]; vt *= ((chunk>>j)&1)? sa[q] : ca[q]; }
    float c0 = ca[pd.qop[0]], s0 = sa[pd.qop[0]], c1 = ca[pd.qop[1]], s1 = sa[pd.qop[1]];
    float cd0 = ca[pd.qop[11]], sd0 = sa[pd.qop[11]];
    float cd1 = ca[pd.qop[12]], sd1 = sa[pd.qop[12]];
    #pragma unroll
    for (int g=0; g<4; g++){
      float vg = vt * ((g&1)? sd0 : cd0) * (((g>>1)&1)? sd1 : cd1);
      a[g*4+0] = make_float2(vg*c0*c1, 0.f);
      a[g*4+1] = make_float2(vg*s0*c1, 0.f);
      a[g*4+2] = make_float2(vg*c0*s1, 0.f);
      a[g*4+3] = make_float2(vg*s0*s1, 0.f);
    }
  } else {
    #pragma unroll
    for (int g=0; g<4; g++){
      u32 s = sb ^ ((g&1)?tD0:0u) ^ (((g>>1)&1)?tD1:0u);
      if (pd.contig){
        u32 p2 = swz(s>>2)*2u;
        float4 v0 = ((float4*)st)[p2], v1 = ((float4*)st)[p2+1];
        float2 w0=make_float2(v0.x,v0.y), w1=make_float2(v0.z,v0.w);
        float2 w2=make_float2(v1.x,v1.y), w3=make_float2(v1.z,v1.w);
        u32 sl = s & 3u;
        if (sl & 1){ float2 t=w0; w0=w1; w1=t; t=w2; w2=w3; w3=t; }
        if (sl & 2){ float2 t=w0; w0=w2; w2=t; t=w1; w1=w3; w3=t; }
        a[g*4+0]=w0; a[g*4+1]=w1; a[g*4+2]=w2; a[g*4+3]=w3;
      } else {
        #pragma unroll
        for (int e=0;e<4;e++){
          u32 se = s ^ ((e&1)?pd.tinv[0]:0u) ^ (((e>>1)&1)?pd.tinv[1]:0u);
          a[g*4+e] = st[swz(se>>2)*4u + (se&3u)];
        }
      }
    }
  }

  APPLY16(0, 16+pd.qop[0]);  APPLY16(1, 16+pd.qop[1]);
  APPLY16(2, 16+pd.qop[11]); APPLY16(3, 16+pd.qop[12]);
  #pragma unroll
  for (int j=0;j<6;j++){
    LANE16(j, 16+pd.qop[2+j]);
  }

  #pragma unroll
  for (int g=0; g<4; g++){
    u32 s = sb ^ ((g&1)?tD0:0u) ^ (((g>>1)&1)?tD1:0u);
    if (pd.contig){
      float2 w0=a[g*4+0], w1=a[g*4+1], w2=a[g*4+2], w3=a[g*4+3];
      u32 sl = s & 3u;
      if (sl & 1){ float2 t=w0; w0=w1; w1=t; t=w2; w2=w3; w3=t; }
      if (sl & 2){ float2 t=w0; w0=w2; w2=t; t=w1; w1=w3; w3=t; }
      u32 p2 = swz(s>>2)*2u;
      ((float4*)st)[p2  ] = make_float4(w0.x,w0.y,w1.x,w1.y);
      ((float4*)st)[p2+1] = make_float4(w2.x,w2.y,w3.x,w3.y);
    } else {
      #pragma unroll
      for (int e=0;e<4;e++){
        u32 se = s ^ ((e&1)?pd.tinv[0]:0u) ^ (((e>>1)&1)?pd.tinv[1]:0u);
        st[swz(se>>2)*4u + (se&3u)] = a[g*4+e];
      }
    }
  }
  __syncthreads();

  // ================= R2b: 3 gates (dirs at positions 8,9 + lane gate at 10) =====
  // thread bits: bit0->pos10, bits1..6->pos2..7, bit7->pos11, bit8->pos12
  {
    u32 sb2 = 0;
    if (tid & 1) sb2 ^= pd.tinv[10];
    #pragma unroll
    for (int j=1;j<7;j++) if ((tid>>j)&1) sb2 ^= pd.tinv[1+j];
    if ((tid>>7)&1) sb2 ^= pd.tinv[11];
    if ((tid>>8)&1) sb2 ^= pd.tinv[12];
    u32 e0m = pd.tinv[8], e1m = pd.tinv[9];
    #pragma unroll
    for (int g=0; g<4; g++){
      u32 s = sb2 ^ ((g&1)?e0m:0u) ^ (((g>>1)&1)?e1m:0u);
      if (pd.contig){
        u32 p2 = swz(s>>2)*2u;
        float4 v0 = ((float4*)st)[p2], v1 = ((float4*)st)[p2+1];
        float2 w0=make_float2(v0.x,v0.y), w1=make_float2(v0.z,v0.w);
        float2 w2=make_float2(v1.x,v1.y), w3=make_float2(v1.z,v1.w);
        u32 sl = s & 3u;
        if (sl & 1){ float2 t=w0; w0=w1; w1=t; t=w2; w2=w3; w3=t; }
        if (sl & 2){ float2 t=w0; w0=w2; w2=t; t=w1; w1=w3; w3=t; }
        a[g*4+0]=w0; a[g*4+1]=w1; a[g*4+2]=w2; a[g*4+3]=w3;
      } else {
        #pragma unroll
        for (int e=0;e<4;e++){
          u32 se = s ^ ((e&1)?pd.tinv[0]:0u) ^ (((e>>1)&1)?pd.tinv[1]:0u);
          a[g*4+e] = st[swz(se>>2)*4u + (se&3u)];
        }
      }
    }
    APPLY16(2, 16+pd.qop[8]); APPLY16(3, 16+pd.qop[9]);
    LANE16(0, 16+pd.qop[10]);
    #pragma unroll
    for (int g=0; g<4; g++){
      u32 s = sb2 ^ ((g&1)?e0m:0u) ^ (((g>>1)&1)?e1m:0u);
      if (pd.contig){
        float2 w0=a[g*4+0], w1=a[g*4+1], w2=a[g*4+2], w3=a[g*4+3];
        u32 sl = s & 3u;
        if (sl & 1){ float2 t=w0; w0=w1; w1=t; t=w2; w2=w3; w3=t; }
        if (sl & 2){ float2 t=w0; w0=w2; w2=t; t=w1; w1=w3; w3=t; }
        u32 p2 = swz(s>>2)*2u;
        ((float4*)st)[p2  ] = make_float4(w0.x,w0.y,w1.x,w1.y);
        ((float4*)st)[p2+1] = make_float4(w2.x,w2.y,w3.x,w3.y);
      } else {
        #pragma unroll
        for (int e=0;e<4;e++){
          u32 se = s ^ ((e&1)?pd.tinv[0]:0u) ^ (((e>>1)&1)?pd.tinv[1]:0u);
          st[swz(se>>2)*4u + (se&3u)] = a[g*4+e];
        }
      }
    }
    __syncthreads();
  }

  // ================= R3: stage-out, applied-CNOT + tau fold on read =================
  {
    u32 ctid = 0, etid = 0;
    #pragma unroll
    for (int j=0;j<9;j++) if ((tid>>j)&1){ ctid ^= pd.cinv[2+j]; etid ^= 1u<<pd.qop[2+j]; }
    #pragma unroll
    for (int j=0;j<3;j++) if ((chunk>>j)&1) etid ^= 1u<<pd.glb[j];
    u32 c11 = pd.cinv[11], c12 = pd.cinv[12];
    u32 q11 = 1u<<pd.qop[11], q12 = 1u<<pd.qop[12];
    #pragma unroll
    for (int j=0;j<4;j++){
      u32 src   = ctid ^ ((j&1)?c11:0u) ^ (((j>>1)&1)?c12:0u);
      u32 ofull = etid ^ ((j&1)?q11:0u) ^ (((j>>1)&1)?q12:0u);
      u32 s0_ = src;
      u32 s1_ = src ^ pd.cinv[0];
      u32 s2_ = src ^ pd.cinv[1];
      u32 s3_ = src ^ pd.cinv[0] ^ pd.cinv[1];
      float2 vv0 = st[swz(s0_>>2)*4u + (s0_&3u)];
      float2 vv1 = st[swz(s1_>>2)*4u + (s1_&3u)];
      float2 vv2 = st[swz(s2_>>2)*4u + (s2_&3u)];
      float2 vv3 = st[swz(s3_>>2)*4u + (s3_&3u)];
      float4* gp = (float4*)(gst + ofull);
      gp[0] = make_float4(vv0.x,vv0.y,vv1.x,vv1.y);
      gp[1] = make_float4(vv2.x,vv2.y,vv3.x,vv3.y);
    }
  }
}

// ======================= host side =======================
// Verified 9-pass schedule (round 2, bench-passed).
static const int Gs[9][3] = {
  {13,14,15},{9,10,11},{2,5,6},{4,7,13},{2,10,14},{6,8,11},{3,9,13},{5,7,14},{10,11,12}
};
static const int Dlen[8] = {4,9,10,10,9,10,9,6};
static const int Dl[8][10] = {
  {12,13,14,15,0,0,0,0,0,0},
  {7,8,9,10,11,12,13,14,15,0},
  {2,3,5,6,8,9,11,12,14,15},
  {0,3,4,7,8,9,11,12,13,15},
  {2,5,7,9,10,12,13,14,15,0},
  {0,2,5,6,8,10,11,12,14,15},
  {2,3,6,9,10,11,12,13,15,0},
  {5,6,7,13,14,15,0,0,0,0},
};

static inline u32 apply_cnot_idx(u32 v, int c, int t){ return v ^ (((v>>c)&1u)<<t); }

extern "C" void kernel_launch(void* const* d_in, const int* in_sizes, int n_in,
                              void* d_out, int out_size, void* d_ws, size_t ws_size,
                              hipStream_t stream)
{
  (void)in_sizes; (void)n_in; (void)ws_size;
  const float* x = (const float*)d_in[0];
  const float* w = (const float*)d_in[1];
  float* out = (float*)d_out;
  float2* state = (float2*)d_ws;   // 512 * 65536 * 8B = 256 MiB

  hipMemsetAsync(d_out, 0, (size_t)out_size*sizeof(float), stream);

  for (int grp=0; grp<NGROUP; grp++){
    for (int p=0; p<9; p++){
      PD pd; memset(&pd, 0, sizeof(pd));
      pd.layerA = p-1;
      pd.layerB = (p<=7)? p : -1;
      pd.mode = (p==0)? 1 : ((p==8)? 2 : 0);
      pd.b0 = grp*GROUPB;

      u32 gm = 0;
      for (int i=0;i<3;i++){ pd.glb[i] = Gs[p][i]; gm |= 1u<<Gs[p][i]; }
      int np=0;
      for (int q=0;q<16;q++) if (!((gm>>q)&1u)) pd.qop[np++] = q;

      // R1 geometry (prev-layer deferred gates)
      if (p >= 1){
        int pos[3], qq[3];
        for (int i=0;i<3;i++){
          int q = Gs[p-1][i]; qq[i] = q;
          int c=0; for (int k=0;k<q;k++) if ((gm>>k)&1u) c++;
          pos[i] = q - c;
        }
        for (int i=0;i<3;i++) for (int k=i+1;k<3;k++)
          if (pos[k] < pos[i]){ int t=pos[i];pos[i]=pos[k];pos[k]=t; t=qq[i];qq[i]=qq[k];qq[k]=t; }
        pd.r1lQ = qq[0];
        pd.r1dPos[0]=pos[1]; pd.r1dQ[0]=qq[1];
        pd.r1dPos[1]=pos[2]; pd.r1dQ[1]=qq[2];
        pd.r1f[0] = pos[0];
        int nf=1;
        for (int pp=2; pp<13; pp++)
          if (pp!=pos[0] && pp!=pos[1] && pp!=pos[2]) pd.r1f[nf++]=pp;
      } else {
        pd.r1lQ = 0;
        pd.r1dPos[0]=11; pd.r1dQ[0]=0;
        pd.r1dPos[1]=12; pd.r1dQ[1]=0;
        for (int j=0;j<9;j++) pd.r1f[j]=2+j;
      }

      // tinv: tau^{-1} (deferred CNOTs of layer p-1, reverse order), local-13
      if (p == 0){
        for (int bp=0;bp<13;bp++) pd.tinv[bp] = 1u<<bp;
      } else {
        int r = p;  // layer (p-1) has r = p
        for (int bp=0;bp<13;bp++){
          u32 v = 1u<<pd.qop[bp];
          for (int i=Dlen[p-1]-1;i>=0;i--){ int c=Dl[p-1][i]; v = apply_cnot_idx(v, c, (c+r)&15); }
          u32 lv=0; for (int rr=0;rr<13;rr++) lv |= ((v>>pd.qop[rr])&1u)<<rr;
          pd.tinv[bp] = lv;
        }
      }
      pd.contig = (pd.tinv[0]==1u && pd.tinv[1]==2u) ? 1 : 0;

      // cinv
      if (p <= 7){
        int r = p+1;
        bool inD[16]; for (int i=0;i<16;i++) inD[i]=false;
        for (int i=0;i<Dlen[p];i++) inD[Dl[p][i]] = true;
        int A[16], na=0;
        for (int i=0;i<16;i++) if (!inD[i]) A[na++]=i;
        for (int bp=0;bp<13;bp++){
          u32 v = 1u<<pd.qop[bp];
          for (int i=na-1;i>=0;i--){ int c=A[i]; v = apply_cnot_idx(v, c, (c+r)&15); }
          if (p >= 1){
            int rp = p;
            for (int i=Dlen[p-1]-1;i>=0;i--){ int c=Dl[p-1][i]; v = apply_cnot_idx(v, c, (c+rp)&15); }
          }
          u32 lv=0; for (int rr=0;rr<13;rr++) lv |= ((v>>pd.qop[rr])&1u)<<rr;
          pd.cinv[bp] = lv;
        }
      } else {
        for (int bp=0;bp<13;bp++){
          u32 v = 1u<<pd.qop[bp];
          for (int i=0;i<Dlen[7];i++){ int c=Dl[7][i]; v = apply_cnot_idx(v, c, (c+8)&15); }
          pd.cinv[bp] = v;
        }
      }

      hipLaunchKernelGGL(qpass, dim3(NCHUNK, GROUPB), dim3(NTHREADS), 0, stream,
                         x, w, state, out, pd);
    }
  }
}

// Round 5
// 2910.532 us; speedup vs baseline: 1.3898x; 1.1234x over previous
//
#include <hip/hip_runtime.h>
#include <cstring>

#define NQ 16
#define NLAYERS 8
#define BATCHN 512
#define GROUPB 128                 // batches per L3-resident group (64 MiB slice)
#define NGROUP (BATCHN/GROUPB)
#define LB 13
#define NLOC (1<<LB)
#define NCHUNK (1<<(NQ-LB))
#define NTHREADS 512

typedef unsigned u32;

// Pass p: [prev-layer 3 deferred Rots] -> [tau = deferred CNOTs folded into LDS gather,
// with chunk-dependent affine masks for global-control gates] -> [13 local Rots]
// -> [applied-CNOT fold on write].
struct PD {
  int layerA, layerB, mode, b0;   // mode: 0 mid, 1 init, 2 fin
  int qop[13];        // qubit at local position
  int glb[3];         // global (chunk) qubits, ascending
  int r1dPos[2];      // R1 tile-dir positions
  int r1dQ[2];        // their qubits
  int r1lQ;           // R1 lane-gate qubit (at tid bit 5)
  int r1f[9];         // R1 thread-bit -> position (bits0-4 lowest free, bit5 = lane pos)
  u32 tinv[13];       // tau^{-1} local masks (raw)
  u32 cinv[13];       // mid: (tau^{-1} o A^{-1}) local; fin: full fwd masks
  u32 tL[13];         // Lmap(tinv)
  u32 cL[13];         // Lmap(cinv) (mid passes)
  u32 tCkL[3];        // chunk-bit affine masks of tau^{-1} (L-mapped local part)
  u32 fCk[3];         // readout: forward tau image of chunk basis (full 16-bit)
  u32 r1em[9];        // global gather masks (1<<qubit)
  u32 r1eL[9];        // LDS write masks (Lmap(1<<pos))
  u32 r1dm[2];        // dir global masks
  u32 r1dLm[2];       // dir LDS masks
};

template<int J>
__device__ __forceinline__ void gate16(float2 (&a)[16],
  float M0r,float M0i,float M1r,float M1i,float M2r,float M2i,float M3r,float M3i){
  #pragma unroll
  for (int i=0;i<16;i++){
    if ((i>>J)&1) continue;
    const int i1 = i|(1<<J);
    float ar=a[i].x, ai=a[i].y, br=a[i1].x, bi=a[i1].y;
    a[i].x  = M0r*ar - M0i*ai + M1r*br - M1i*bi;
    a[i].y  = M0r*ai + M0i*ar + M1r*bi + M1i*br;
    a[i1].x = M2r*ar - M2i*ai + M3r*br - M3i*bi;
    a[i1].y = M2r*ai + M2i*ar + M3r*bi + M3i*br;
  }
}

__device__ __forceinline__ void lane_gate16(float2 (&a)[16], int tid, int j,
  float r0,float i0,float r1,float i1,float r2,float i2,float r3,float i3){
  int bit = (tid >> j) & 1;
  float cAr = bit? r3 : r0, cAi = bit? i3 : i0;
  float cBr = bit? r2 : r1, cBi = bit? i2 : i1;
  #pragma unroll
  for (int i=0;i<16;i++){
    float tx = __shfl_xor(a[i].x, 1<<j);
    float ty = __shfl_xor(a[i].y, 1<<j);
    float ax = a[i].x, ay = a[i].y;
    a[i].x = cAr*ax - cAi*ay + cBr*tx - cBi*ty;
    a[i].y = cAr*ay + cAi*ax + cBr*ty + cBi*tx;
  }
}

#define APPLY16(J, SRC) { \
  int _s = (SRC); \
  float r0_=__shfl(mm0,_s), i0_=__shfl(mm1,_s), r1_=__shfl(mm2,_s), i1_=__shfl(mm3,_s); \
  float r2_=__shfl(mm4,_s), i2_=__shfl(mm5,_s), r3_=__shfl(mm6,_s), i3_=__shfl(mm7,_s); \
  gate16<J>(a, r0_,i0_,r1_,i1_,r2_,i2_,r3_,i3_); }

#define LANE16(J, SRC) { \
  int _s = (SRC); \
  float r0_=__shfl(mm0,_s), i0_=__shfl(mm1,_s), r1_=__shfl(mm2,_s), i1_=__shfl(mm3,_s); \
  float r2_=__shfl(mm4,_s), i2_=__shfl(mm5,_s), r3_=__shfl(mm6,_s), i3_=__shfl(mm7,_s); \
  lane_gate16(a, tid, (J), r0_,i0_,r1_,i1_,r2_,i2_,r3_,i3_); }

__global__ __launch_bounds__(NTHREADS, 4)
void qpass(const float* __restrict__ x, const float* __restrict__ w,
           float2* __restrict__ state, float* __restrict__ out, PD pd)
{
  __shared__ __align__(16) float2 st[NLOC];   // 64 KB
  const int tid = threadIdx.x;
  const u32 chunk = blockIdx.x;
  const int b = pd.b0 + blockIdx.y;
  float2* __restrict__ gst = state + ((size_t)b << NQ);

  // per-lane Rot matrices: lanes 0-15 = layerA (prev), 16-31 = layerB (cur)
  float mm0,mm1,mm2,mm3,mm4,mm5,mm6,mm7;
  {
    int lane = tid & 63;
    int q = lane & 15;
    int lay = ((lane>>4)&1) ? pd.layerB : pd.layerA;
    if (lay < 0) lay = 0;
    float phi = w[(lay*NQ+q)*3+0], th = w[(lay*NQ+q)*3+1], om = w[(lay*NQ+q)*3+2];
    float sh, ch; sincosf(0.5f*th, &sh, &ch);
    float spo, cpo; sincosf(-0.5f*(phi+om), &spo, &cpo);
    float smo, cmo; sincosf(-0.5f*(phi-om), &smo, &cmo);
    mm0 =  cpo*ch; mm1 =  spo*ch;
    mm2 = -cmo*sh; mm3 =  smo*sh;
    mm4 =  cmo*sh; mm5 =  smo*sh;
    mm6 =  cpo*ch; mm7 = -spo*ch;
  }

  // chunk-dependent affine part of tau^{-1} (L-mapped)
  u32 ckL = 0;
  if (chunk & 1) ckL ^= pd.tCkL[0];
  if (chunk & 2) ckL ^= pd.tCkL[1];
  if (chunk & 4) ckL ^= pd.tCkL[2];

  float2 a[16];

  // ================= R1: coalesced global gather + 3 prev-layer deferred Rots =====
  if (pd.mode != 1){
    u32 ebase = 0, lbL = 0;
    #pragma unroll
    for (int j=0;j<9;j++) if ((tid>>j)&1){ ebase ^= pd.r1em[j]; lbL ^= pd.r1eL[j]; }
    #pragma unroll
    for (int j=0;j<3;j++) if ((chunk>>j)&1) ebase ^= 1u<<pd.glb[j];
    #pragma unroll
    for (int g=0; g<4; g++){
      u32 full = ebase ^ ((g&1)?pd.r1dm[0]:0u) ^ (((g>>1)&1)?pd.r1dm[1]:0u);
      const float4* gp = (const float4*)(gst + full);
      float4 v0 = gp[0], v1 = gp[1];
      a[g*4+0] = make_float2(v0.x,v0.y); a[g*4+1] = make_float2(v0.z,v0.w);
      a[g*4+2] = make_float2(v1.x,v1.y); a[g*4+3] = make_float2(v1.z,v1.w);
    }
    APPLY16(2, pd.r1dQ[0]);
    APPLY16(3, pd.r1dQ[1]);
    LANE16(5, pd.r1lQ);

    if (pd.mode == 2){
      // -------- readout: |amp|^2, full forward masks in cinv; chunk via fCk --------
      float acc[NQ];
      #pragma unroll
      for (int q=0;q<NQ;q++) acc[q]=0.f;
      u32 nb = 0;
      #pragma unroll
      for (int j=0;j<9;j++) if ((tid>>j)&1) nb ^= pd.cinv[pd.r1f[j]];
      #pragma unroll
      for (int j=0;j<3;j++) if ((chunk>>j)&1) nb ^= pd.fCk[j];
      u32 cd0 = pd.cinv[pd.r1dPos[0]], cd1 = pd.cinv[pd.r1dPos[1]];
      #pragma unroll
      for (int g=0; g<4; g++){
        u32 n0 = nb ^ ((g&1)?cd0:0u) ^ (((g>>1)&1)?cd1:0u);
        #pragma unroll
        for (int e=0;e<4;e++){
          u32 n = n0 ^ ((e&1)?pd.cinv[0]:0u) ^ (((e>>1)&1)?pd.cinv[1]:0u);
          float2 v = a[g*4+e];
          float p = v.x*v.x + v.y*v.y;
          #pragma unroll
          for (int q=0;q<NQ;q++) acc[q] += ((n>>q)&1u) ? -p : p;
        }
      }
      #pragma unroll
      for (int q=0;q<NQ;q++){
        float v = acc[q];
        #pragma unroll
        for (int off=32; off; off>>=1) v += __shfl_xor(v, off);
        if ((tid & 63) == 0) atomicAdd(&out[b*NQ+q], v);
      }
      return;
    }

    // write tile to LDS (logical pre-tau layout)
    #pragma unroll
    for (int g=0; g<4; g++){
      u32 mL = lbL ^ ((g&1)?pd.r1dLm[0]:0u) ^ (((g>>1)&1)?pd.r1dLm[1]:0u);
      ((float4*)st)[(mL>>1)  ] = make_float4(a[g*4+0].x,a[g*4+0].y,a[g*4+1].x,a[g*4+1].y);
      ((float4*)st)[(mL>>1)+1] = make_float4(a[g*4+2].x,a[g*4+2].y,a[g*4+3].x,a[g*4+3].y);
    }
    __syncthreads();
  }

  // ================= R2: 10 gates (2 e + 2 dir + 6 lane) =================
  u32 sbL = ckL;
  #pragma unroll
  for (int j=0;j<9;j++) if ((tid>>j)&1) sbL ^= pd.tL[2+j];
  const u32 Ltd0 = pd.tL[11], Ltd1 = pd.tL[12], Le0 = pd.tL[0], Le1 = pd.tL[1];

  if (pd.mode == 1){
    // embed: product state directly in R2 layout (tau = identity at p=0)
    float ca[NQ], sa[NQ];
    #pragma unroll
    for (int q=0;q<NQ;q++){
      float aa = 1.57079632679489662f * x[b*NQ+q];
      sincosf(aa, &sa[q], &ca[q]);
    }
    float vt = 1.f;
    #pragma unroll
    for (int j=0;j<9;j++){ int q = pd.qop[2+j]; vt *= ((tid>>j)&1)? sa[q] : ca[q]; }
    #pragma unroll
    for (int j=0;j<3;j++){ int q = pd.glb[j]; vt *= ((chunk>>j)&1)? sa[q] : ca[q]; }
    float c0 = ca[pd.qop[0]], s0 = sa[pd.qop[0]], c1 = ca[pd.qop[1]], s1 = sa[pd.qop[1]];
    float cd0 = ca[pd.qop[11]], sd0 = sa[pd.qop[11]];
    float cd1 = ca[pd.qop[12]], sd1 = sa[pd.qop[12]];
    #pragma unroll
    for (int g=0; g<4; g++){
      float vg = vt * ((g&1)? sd0 : cd0) * (((g>>1)&1)? sd1 : cd1);
      a[g*4+0] = make_float2(vg*c0*c1, 0.f);
      a[g*4+1] = make_float2(vg*s0*c1, 0.f);
      a[g*4+2] = make_float2(vg*c0*s1, 0.f);
      a[g*4+3] = make_float2(vg*s0*s1, 0.f);
    }
  } else {
    #pragma unroll
    for (int g=0; g<4; g++){
      u32 sL = sbL ^ ((g&1)?Ltd0:0u) ^ (((g>>1)&1)?Ltd1:0u);
      a[g*4+0] = st[sL];
      a[g*4+1] = st[sL^Le0];
      a[g*4+2] = st[sL^Le1];
      a[g*4+3] = st[sL^Le0^Le1];
    }
  }

  APPLY16(0, 16+pd.qop[0]);  APPLY16(1, 16+pd.qop[1]);
  APPLY16(2, 16+pd.qop[11]); APPLY16(3, 16+pd.qop[12]);
  #pragma unroll
  for (int j=0;j<6;j++){
    LANE16(j, 16+pd.qop[2+j]);
  }

  #pragma unroll
  for (int g=0; g<4; g++){
    u32 sL = sbL ^ ((g&1)?Ltd0:0u) ^ (((g>>1)&1)?Ltd1:0u);
    st[sL]         = a[g*4+0];
    st[sL^Le0]     = a[g*4+1];
    st[sL^Le1]     = a[g*4+2];
    st[sL^Le0^Le1] = a[g*4+3];
  }
  __syncthreads();

  // ================= R2b: 3 gates (dirs at pos 8,9 + lane gate at pos 10) =====
  // thread bits: bit0->pos10, bits1..6->pos2..7, bit7->pos11, bit8->pos12
  {
    u32 s2L = ckL;
    if (tid & 1) s2L ^= pd.tL[10];
    #pragma unroll
    for (int j=1;j<7;j++) if ((tid>>j)&1) s2L ^= pd.tL[1+j];
    if ((tid>>7)&1) s2L ^= pd.tL[11];
    if ((tid>>8)&1) s2L ^= pd.tL[12];
    const u32 LD0 = pd.tL[8], LD1 = pd.tL[9];
    #pragma unroll
    for (int g=0; g<4; g++){
      u32 sL = s2L ^ ((g&1)?LD0:0u) ^ (((g>>1)&1)?LD1:0u);
      a[g*4+0] = st[sL];
      a[g*4+1] = st[sL^Le0];
      a[g*4+2] = st[sL^Le1];
      a[g*4+3] = st[sL^Le0^Le1];
    }
    APPLY16(2, 16+pd.qop[8]); APPLY16(3, 16+pd.qop[9]);
    LANE16(0, 16+pd.qop[10]);
    #pragma unroll
    for (int g=0; g<4; g++){
      u32 sL = s2L ^ ((g&1)?LD0:0u) ^ (((g>>1)&1)?LD1:0u);
      st[sL]         = a[g*4+0];
      st[sL^Le0]     = a[g*4+1];
      st[sL^Le1]     = a[g*4+2];
      st[sL^Le0^Le1] = a[g*4+3];
    }
    __syncthreads();
  }

  // ================= R3: coalesced stage-out, (tau^-1 o A^-1) fold on LDS read =====
  {
    u32 ctL = ckL, etid = 0;
    #pragma unroll
    for (int j=0;j<9;j++) if ((tid>>j)&1){ ctL ^= pd.cL[2+j]; etid ^= 1u<<pd.qop[2+j]; }
    #pragma unroll
    for (int j=0;j<3;j++) if ((chunk>>j)&1) etid ^= 1u<<pd.glb[j];
    const u32 Lc0 = pd.cL[0], Lc1 = pd.cL[1];
    const u32 Lc11 = pd.cL[11], Lc12 = pd.cL[12];
    const u32 q11 = 1u<<pd.qop[11], q12 = 1u<<pd.qop[12];
    #pragma unroll
    for (int j=0;j<4;j++){
      u32 srcL  = ctL  ^ ((j&1)?Lc11:0u) ^ (((j>>1)&1)?Lc12:0u);
      u32 ofull = etid ^ ((j&1)?q11:0u)  ^ (((j>>1)&1)?q12:0u);
      float2 vv0 = st[srcL];
      float2 vv1 = st[srcL^Lc0];
      float2 vv2 = st[srcL^Lc1];
      float2 vv3 = st[srcL^Lc0^Lc1];
      float4* gp = (float4*)(gst + ofull);
      gp[0] = make_float4(vv0.x,vv0.y,vv1.x,vv1.y);
      gp[1] = make_float4(vv2.x,vv2.y,vv3.x,vv3.y);
    }
  }
}

// ======================= host side =======================
// Hand-verified schedule: globals high (coalesced), deferred targets always local
// in the next pass; global-CONTROL deferred gates handled via tCkL chunk masks.
static const int Gs[9][3] = {
  {13,14,15},{8,10,12},{11,13,15},{8,9,10},{7,11,15},{8,9,10},{11,12,13},{8,9,10},{13,14,15}
};
static const int Dlen[8] = {4,5,7,9,8,10,8,6};
static const int Dl[8][10] = {
  {12,13,14,15,0,0,0,0,0,0},
  {6,8,10,12,14,0,0,0,0,0},
  {8,10,11,12,13,14,15,0,0,0},
  {4,5,6,8,9,10,12,13,14,0},
  {2,6,7,10,11,12,13,15,0,0},
  {2,3,4,8,9,10,12,13,14,15},
  {4,5,6,11,12,13,14,15,0,0},
  {0,1,2,8,9,10,0,0,0,0},
};

static inline u32 apply_cnot_idx(u32 v, int c, int t){ return v ^ (((v>>c)&1u)<<t); }
static inline u32 h_swz(u32 q){ return q ^ ((q>>3)&7u); }
static inline u32 h_Lmap(u32 m){ return (h_swz(m>>2)<<2) | (m&3u); }

extern "C" void kernel_launch(void* const* d_in, const int* in_sizes, int n_in,
                              void* d_out, int out_size, void* d_ws, size_t ws_size,
                              hipStream_t stream)
{
  (void)in_sizes; (void)n_in; (void)ws_size;
  const float* x = (const float*)d_in[0];
  const float* w = (const float*)d_in[1];
  float* out = (float*)d_out;
  float2* state = (float2*)d_ws;   // 512 * 65536 * 8B = 256 MiB

  hipMemsetAsync(d_out, 0, (size_t)out_size*sizeof(float), stream);

  for (int grp=0; grp<NGROUP; grp++){
    for (int p=0; p<9; p++){
      PD pd; memset(&pd, 0, sizeof(pd));
      pd.layerA = p-1;
      pd.layerB = (p<=7)? p : -1;
      pd.mode = (p==0)? 1 : ((p==8)? 2 : 0);
      pd.b0 = grp*GROUPB;

      u32 gm = 0;
      for (int i=0;i<3;i++){ pd.glb[i] = Gs[p][i]; gm |= 1u<<Gs[p][i]; }
      int np=0;
      for (int q=0;q<16;q++) if (!((gm>>q)&1u)) pd.qop[np++] = q;

      // R1 geometry (prev-layer deferred Rot gates)
      if (p >= 1){
        int pos[3], qq[3];
        for (int i=0;i<3;i++){
          int q = Gs[p-1][i]; qq[i] = q;
          int c=0; for (int k=0;k<q;k++) if ((gm>>k)&1u) c++;
          pos[i] = q - c;
        }
        for (int i=0;i<3;i++) for (int k=i+1;k<3;k++)
          if (pos[k] < pos[i]){ int t=pos[i];pos[i]=pos[k];pos[k]=t; t=qq[i];qq[i]=qq[k];qq[k]=t; }
        pd.r1lQ = qq[0];
        pd.r1dPos[0]=pos[1]; pd.r1dQ[0]=qq[1];
        pd.r1dPos[1]=pos[2]; pd.r1dQ[1]=qq[2];
        int free_[9], nf=0;
        for (int pp=2; pp<13; pp++)
          if (pp!=pos[0] && pp!=pos[1] && pp!=pos[2]) free_[nf++]=pp;   // 8 entries
        for (int j=0;j<5;j++) pd.r1f[j]=free_[j];   // bits 0-4: lowest positions
        pd.r1f[5]=pos[0];                            // bit 5: lane-gate position
        for (int j=0;j<3;j++) pd.r1f[6+j]=free_[5+j];
      } else {
        pd.r1lQ = 0;
        pd.r1dPos[0]=11; pd.r1dQ[0]=0;
        pd.r1dPos[1]=12; pd.r1dQ[1]=0;
        for (int j=0;j<5;j++) pd.r1f[j]=2+j;
        pd.r1f[5]=10; pd.r1f[6]=7; pd.r1f[7]=8; pd.r1f[8]=9;
      }

      // tinv: tau^{-1} on local basis (deferred CNOTs of layer p-1, reverse order)
      if (p == 0){
        for (int bp=0;bp<13;bp++) pd.tinv[bp] = 1u<<bp;
        for (int j=0;j<3;j++) pd.tCkL[j] = 0u;
      } else {
        int r = p;  // layer (p-1) has r = p
        for (int bp=0;bp<13;bp++){
          u32 v = 1u<<pd.qop[bp];
          for (int i=Dlen[p-1]-1;i>=0;i--){ int c=Dl[p-1][i]; v = apply_cnot_idx(v, c, (c+r)&15); }
          u32 lv=0; for (int rr=0;rr<13;rr++) lv |= ((v>>pd.qop[rr])&1u)<<rr;
          pd.tinv[bp] = lv;
        }
        // chunk-basis affine part: image of chunk qubit under tau^{-1}, local component
        for (int j=0;j<3;j++){
          u32 v = 1u<<pd.glb[j];
          for (int i=Dlen[p-1]-1;i>=0;i--){ int c=Dl[p-1][i]; v = apply_cnot_idx(v, c, (c+r)&15); }
          v &= ~(1u<<pd.glb[j]);      // chunk bit passes through; keep local part
          u32 lv=0; for (int rr=0;rr<13;rr++) lv |= ((v>>pd.qop[rr])&1u)<<rr;
          pd.tCkL[j] = h_Lmap(lv);
        }
      }

      // cinv
      if (p <= 7){
        int r = p+1;
        bool inD[16]; for (int i=0;i<16;i++) inD[i]=false;
        for (int i=0;i<Dlen[p];i++) inD[Dl[p][i]] = true;
        int A[16], na=0;
        for (int i=0;i<16;i++) if (!inD[i]) A[na++]=i;
        for (int bp=0;bp<13;bp++){
          u32 v = 1u<<pd.qop[bp];
          for (int i=na-1;i>=0;i--){ int c=A[i]; v = apply_cnot_idx(v, c, (c+r)&15); }
          if (p >= 1){
            int rp = p;
            for (int i=Dlen[p-1]-1;i>=0;i--){ int c=Dl[p-1][i]; v = apply_cnot_idx(v, c, (c+rp)&15); }
          }
          u32 lv=0; for (int rr=0;rr<13;rr++) lv |= ((v>>pd.qop[rr])&1u)<<rr;
          pd.cinv[bp] = lv;
        }
        for (int j=0;j<3;j++) pd.fCk[j] = 0u;
      } else {
        // readout: full forward tau (D_7 ascending, r=8), uncompressed 16-bit
        for (int bp=0;bp<13;bp++){
          u32 v = 1u<<pd.qop[bp];
          for (int i=0;i<Dlen[7];i++){ int c=Dl[7][i]; v = apply_cnot_idx(v, c, (c+8)&15); }
          pd.cinv[bp] = v;
        }
        for (int j=0;j<3;j++){
          u32 v = 1u<<pd.glb[j];
          for (int i=0;i<Dlen[7];i++){ int c=Dl[7][i]; v = apply_cnot_idx(v, c, (c+8)&15); }
          pd.fCk[j] = v;
        }
      }

      // L-mapped precomputes
      for (int k=0;k<13;k++){
        pd.tL[k] = h_Lmap(pd.tinv[k]);
        pd.cL[k] = (p<=7) ? h_Lmap(pd.cinv[k]) : 0u;
      }
      for (int j=0;j<9;j++){
        pd.r1em[j] = 1u<<pd.qop[pd.r1f[j]];
        pd.r1eL[j] = h_Lmap(1u<<pd.r1f[j]);
      }
      for (int j=0;j<2;j++){
        pd.r1dm[j]  = 1u<<pd.qop[pd.r1dPos[j]];
        pd.r1dLm[j] = h_Lmap(1u<<pd.r1dPos[j]);
      }

      hipLaunchKernelGGL(qpass, dim3(NCHUNK, GROUPB), dim3(NTHREADS), 0, stream,
                         x, w, state, out, pd);
    }
  }
}